// Round 14
// baseline (83.254 us; speedup 1.0000x reference)
//
#include <hip/hip_runtime.h>

typedef unsigned int u32;
typedef unsigned short u16;
typedef __fp16 h2 __attribute__((ext_vector_type(2)));
typedef __fp16 f16x8 __attribute__((ext_vector_type(8)));
typedef float f32x4 __attribute__((ext_vector_type(4)));

#define DEVFN static __device__ __forceinline__

DEVFN u32 pkh(float a, float b) {
  return __builtin_bit_cast(u32, __builtin_amdgcn_cvt_pkrtz(a, b));
}
DEVFN u16 f2h(float f) { __fp16 h = (__fp16)f; return __builtin_bit_cast(u16, h); }

#if __has_builtin(__builtin_amdgcn_fdot2)
DEVFN float dot2u(u32 a, u32 b, float c) {
  return __builtin_amdgcn_fdot2(__builtin_bit_cast(h2, a),
                                __builtin_bit_cast(h2, b), c, false);
}
#else
DEVFN float dot2u(u32 a, u32 b, float c) {
  h2 x = __builtin_bit_cast(h2, a), y = __builtin_bit_cast(h2, b);
  return c + (float)x[0] * (float)y[0] + (float)x[1] * (float)y[1];
}
#endif

DEVFN uint4 pk8(f32x4 lo, f32x4 hi) {
  uint4 o;
  o.x = pkh(lo.x, lo.y); o.y = pkh(lo.z, lo.w);
  o.z = pkh(hi.x, hi.y); o.w = pkh(hi.z, hi.w);
  return o;
}

DEVFN void gld16(const u16* g, u16* l) {
  __builtin_amdgcn_global_load_lds(
      (const __attribute__((address_space(1))) u32*)g,
      (__attribute__((address_space(3))) u32*)l, 16, 0, 0);
}

DEVFN void waitl0() { asm volatile("s_waitcnt lgkmcnt(0)" ::: "memory"); }
DEVFN void rbar() {
  __builtin_amdgcn_sched_barrier(0);
  __builtin_amdgcn_s_barrier();
  __builtin_amdgcn_sched_barrier(0);
}

// C = A @ B^T.  (identical to round-13 verified template)
// F32=1 (gemm1): f32 reg-staged dbuf write-late raw-barrier pipeline.
// F32=0 (gemm2): f16 gld16, BK=64 as two [128][32] subtiles per barrier round.
// MODE 0: L2-normalize each aligned 64-col group; write f16 PLANAR qf. Nn=1024
// MODE 1: add f32 bias[col]; Out = f32 row-major [M][Nn]
template <int MODE, int F32, int TN>
__global__ __launch_bounds__(256) void gemm(
    const void* __restrict__ A_, const void* __restrict__ B_,
    const float* __restrict__ bias, void* __restrict__ Out_,
    int Nn, int K) {
  __shared__ u16 As[2][4096];
  __shared__ u16 Bs[2][4096];
  const int tid = threadIdx.x;
  const int lane = tid & 63;
  const int w = tid >> 6;
  const int wm = w >> 1, wn = w & 1;
  const int nwg = (int)gridDim.x;
  const int wg = ((int)blockIdx.x & 7) * (nwg >> 3) + ((int)blockIdx.x >> 3);
  const int tm = wg / TN, tn = wg % TN;

  const float* Af = (const float*)A_;
  const float* Bf = (const float*)B_;
  const u16* Ah = (const u16*)A_;
  const u16* Bh = (const u16*)B_;

  const int rr = tid >> 2;
  const int s8 = (tid & 3) << 3;
  const size_t offA = (size_t)(tm * 128 + rr) * K + s8;
  const size_t offB = (size_t)(tn * 128 + rr) * K + s8;
  const int wofs = rr * 32 + s8;

  const int sr = w * 32 + (lane >> 2);
  const int sc = (lane & 3) << 3;
  const u16* gA = Ah + (size_t)(tm * 128 + sr) * K + sc;
  const u16* gB = Bh + (size_t)(tn * 128 + sr) * K + sc;

  const int rofsA = ((wm * 64 + (lane & 15)) << 5) + ((lane >> 4) << 3);
  const int rofsB = ((wn * 64 + (lane & 15)) << 5) + ((lane >> 4) << 3);

  f32x4 acc[4][4] = {};

  f32x4 a0, a1, a2, a3, b0, b1, b2, b3;

#define LOADF(t)                                                          \
  {                                                                       \
    const size_t oa = offA + (size_t)(t) * 32;                            \
    const size_t ob = offB + (size_t)(t) * 32;                            \
    a0 = *(const f32x4*)(Af + oa);                                        \
    a1 = *(const f32x4*)(Af + oa + 4);                                    \
    a2 = *(const f32x4*)(Af + oa + (size_t)64 * K);                       \
    a3 = *(const f32x4*)(Af + oa + (size_t)64 * K + 4);                   \
    b0 = *(const f32x4*)(Bf + ob);                                        \
    b1 = *(const f32x4*)(Bf + ob + 4);                                    \
    b2 = *(const f32x4*)(Bf + ob + (size_t)64 * K);                       \
    b3 = *(const f32x4*)(Bf + ob + (size_t)64 * K + 4);                   \
  }
#define WRITEF(bufi)                                                      \
  {                                                                       \
    u16* da = &As[bufi][wofs];                                            \
    u16* db = &Bs[bufi][wofs];                                            \
    *(uint4*)da = pk8(a0, a1);                                            \
    *(uint4*)(da + 2048) = pk8(a2, a3);                                   \
    *(uint4*)db = pk8(b0, b1);                                            \
    *(uint4*)(db + 2048) = pk8(b2, b3);                                   \
  }
#define STAGEH(bufi, t)                                                   \
  {                                                                       \
    gld16(gA + (size_t)(t) * 32, &As[bufi][w * 1024]);                    \
    gld16(gA + (size_t)(t) * 32 + (size_t)16 * K, &As[bufi][w * 1024 + 512]); \
    gld16(gB + (size_t)(t) * 32, &Bs[bufi][w * 1024]);                    \
    gld16(gB + (size_t)(t) * 32 + (size_t)16 * K, &Bs[bufi][w * 1024 + 512]); \
  }

  if (F32) {
    const int KT = K >> 5;
    LOADF(0)
    WRITEF(0)
    LOADF(1)
    waitl0();
    rbar();
    for (int kt = 0; kt < KT; ++kt) {
      const int cur = kt & 1;
      f16x8 af[4], bf[4];
#pragma unroll
      for (int i = 0; i < 4; ++i) af[i] = *(const f16x8*)(&As[cur][rofsA + i * 512]);
#pragma unroll
      for (int i = 0; i < 4; ++i) bf[i] = *(const f16x8*)(&Bs[cur][rofsB + i * 512]);
      if (kt + 1 < KT) {
        WRITEF(cur ^ 1)
        if (kt + 2 < KT) LOADF(kt + 2)
      }
      __builtin_amdgcn_s_setprio(1);
#pragma unroll
      for (int mi = 0; mi < 4; ++mi)
#pragma unroll
        for (int ni = 0; ni < 4; ++ni)
          acc[mi][ni] = __builtin_amdgcn_mfma_f32_16x16x32_f16(af[mi], bf[ni],
                                                               acc[mi][ni], 0, 0, 0);
      __builtin_amdgcn_s_setprio(0);
      waitl0();
      rbar();
    }
  } else {
    const int KT = K >> 6;
    for (int kt = 0; kt < KT; ++kt) {
      __syncthreads();
      STAGEH(0, 2 * kt)
      STAGEH(1, 2 * kt + 1)
      __syncthreads();
#pragma unroll
      for (int sub = 0; sub < 2; ++sub) {
        f16x8 af[4], bf[4];
#pragma unroll
        for (int i = 0; i < 4; ++i)
          af[i] = *(const f16x8*)(&As[sub][rofsA + i * 512]);
#pragma unroll
        for (int i = 0; i < 4; ++i)
          bf[i] = *(const f16x8*)(&Bs[sub][rofsB + i * 512]);
#pragma unroll
        for (int mi = 0; mi < 4; ++mi)
#pragma unroll
          for (int ni = 0; ni < 4; ++ni)
            acc[mi][ni] = __builtin_amdgcn_mfma_f32_16x16x32_f16(
                af[mi], bf[ni], acc[mi][ni], 0, 0, 0);
      }
    }
  }
#undef LOADF
#undef WRITEF
#undef STAGEH

  const int rowBase = tm * 128 + wm * 64 + ((lane >> 4) << 2);
  const int colBase = tn * 128 + wn * 64 + (lane & 15);

  if (MODE == 1) {
    float* Out = (float*)Out_;
    float bv[4];
#pragma unroll
    for (int ni = 0; ni < 4; ++ni) bv[ni] = bias[colBase + ni * 16];
#pragma unroll
    for (int mi = 0; mi < 4; ++mi)
#pragma unroll
      for (int r = 0; r < 4; ++r) {
        size_t ro = (size_t)(rowBase + mi * 16 + r) * Nn;
#pragma unroll
        for (int ni = 0; ni < 4; ++ni)
          Out[ro + colBase + ni * 16] = acc[mi][ni][r] + bv[ni];
      }
  } else {
    u16* Out = (u16*)Out_;
    const int sel = colBase >> 9;
    const int hh = (colBase >> 6) & 7;
    const int ddb = lane & 15;
#pragma unroll
    for (int mi = 0; mi < 4; ++mi)
#pragma unroll
      for (int r = 0; r < 4; ++r) {
        float s = acc[mi][0][r] * acc[mi][0][r] + acc[mi][1][r] * acc[mi][1][r] +
                  acc[mi][2][r] * acc[mi][2][r] + acc[mi][3][r] * acc[mi][3][r];
        s += __shfl_xor(s, 1);
        s += __shfl_xor(s, 2);
        s += __shfl_xor(s, 4);
        s += __shfl_xor(s, 8);
        float inv = 1.0f / fmaxf(sqrtf(s), 1e-12f);
        const int m = rowBase + mi * 16 + r;
        const int bb = m >> 13, tt = (m >> 10) & 7, pix = m & 1023;
        const int fr = ((sel * 2 + bb) * 8 + tt) * 8 + hh;
        size_t base = (((size_t)fr) << 16) + (size_t)pix * 64 + ddb;
#pragma unroll
        for (int ni = 0; ni < 4; ++ni)
          Out[base + ni * 16] = f2h(acc[mi][ni][r] * inv);
      }
  }
}

// full 64-ch dot: 8 uint4 k-vector vs 32-u32 q
DEVFN float dot64(const u32* qw, const uint4* kv) {
  float s0 = 0.f, s1 = 0.f, s2 = 0.f, s3 = 0.f;
#pragma unroll
  for (int j = 0; j < 8; ++j) {
    s0 = dot2u(qw[j * 4 + 0], kv[j].x, s0);
    s1 = dot2u(qw[j * 4 + 1], kv[j].y, s1);
    s2 = dot2u(qw[j * 4 + 2], kv[j].z, s2);
    s3 = dot2u(qw[j * 4 + 3], kv[j].w, s3);
  }
  return (s0 + s1) + (s2 + s3);
}

// Merged kernel, 128 threads/block.
// blocks 0..511: dots with PX-PAIRING — each thread computes 2 adjacent px;
//   their 7-col k-windows overlap 6/7 -> 8 col-reads serve 14 dots (-43% LDS).
//   corr layout [tok][448], col = h*56 + du*8 + dv (dv==7 zero; matches W2).
// blocks 512..1023: W2[512][448] + cvec prep.
__global__ __launch_bounds__(128) void dots_w2(
    const u16* __restrict__ qf, u16* __restrict__ corr,
    const float* __restrict__ wp, const float* __restrict__ wc,
    const float* __restrict__ bc, const float* __restrict__ bp,
    u16* __restrict__ W2, float* __restrict__ cvec) {
  __shared__ __align__(16) u16 smem[448 * 64];  // 56KB
  const int tid = threadIdx.x;

  if ((int)blockIdx.x >= 512) {
    // ---- W2/cvec prep ----
    const int o = (int)blockIdx.x - 512;
    float* wcl = (float*)smem;        // [64*49]
    float* wpl = wcl + 3136;          // [512]
    for (int i = tid; i < 3136; i += 128) wcl[i] = wc[i];
    for (int i = tid; i < 512; i += 128) wpl[i] = wp[o * 512 + i];
    __syncthreads();
#pragma unroll
    for (int pass = 0; pass < 4; ++pass) {
      const int idx = pass * 128 + tid;      // 0..511
      if (idx < 448) {
        const int hh = idx / 56, r = idx % 56, du = r >> 3, dv = r & 7;
        float sv = 0.f;
        if (dv < 7) {
#pragma unroll
          for (int c = 0; c < 64; ++c)
            sv += wpl[hh * 64 + c] * wcl[c * 49 + du * 7 + dv];
        }
        W2[o * 448 + idx] = f2h(sv);
      }
    }
    if (tid < 64) {
      float p = 0.f;
#pragma unroll
      for (int g = 0; g < 8; ++g) p += wpl[g * 64 + tid];
      p *= bc[tid];
      p += __shfl_xor(p, 1); p += __shfl_xor(p, 2); p += __shfl_xor(p, 4);
      p += __shfl_xor(p, 8); p += __shfl_xor(p, 16); p += __shfl_xor(p, 32);
      if (tid == 0) cvec[o] = p + bp[o];
    }
    return;
  }

  // ---- dots (px-paired) ----
  u16* kst = smem;
  const int bid = ((int)blockIdx.x & 7) * 64 + ((int)blockIdx.x >> 3);  // XCD
  const int fr = bid >> 2, grp = bid & 3;
  const int h = fr & 7, t = (fr >> 3) & 7, b = fr >> 6;
  const int t1 = (t < 7) ? t + 1 : 7;
  const int y0 = grp * 8;

  // stage 14 k-rows (zero OOB), swizzle byte ^= (pl&7)<<4; 28 passes x 16 px
  const u16* kbase = qf + (((size_t)(((2 + b) * 8 + t1) * 8 + h)) << 16);
  {
    const int ppx = tid >> 3;        // 0..15
    const int slot = tid & 7;
#pragma unroll
    for (int pass = 0; pass < 28; ++pass) {
      int pl = pass * 16 + ppx;      // 0..447
      int gy = y0 - 3 + (pl >> 5);
      int gx = pl & 31;
      uint4 v = make_uint4(0, 0, 0, 0);
      if ((unsigned)gy < 32u)
        v = *(const uint4*)(kbase + (size_t)(gy * 32 + gx) * 64 + slot * 8);
      *(uint4*)((char*)kst + pl * 128 + ((slot * 16) ^ ((pl & 7) << 4))) = v;
    }
  }

  // q pair: thread covers px0 = 2*xh, px1 = 2*xh+1 within its row
  const int xh = tid & 15, yloc = tid >> 4;       // yloc 0..7
  const int px0 = grp * 256 + yloc * 32 + 2 * xh;
  const int x0 = 2 * xh;                          // col of px0 (0..30)
  const u16* qp = qf + (((size_t)fr) << 16) + (size_t)px0 * 64;
  u32 qw0[32], qw1[32];
#pragma unroll
  for (int j = 0; j < 8; ++j) {
    uint4 v = *(const uint4*)(qp + j * 8);
    qw0[j * 4 + 0] = v.x; qw0[j * 4 + 1] = v.y;
    qw0[j * 4 + 2] = v.z; qw0[j * 4 + 3] = v.w;
  }
#pragma unroll
  for (int j = 0; j < 8; ++j) {
    uint4 v = *(const uint4*)(qp + 64 + j * 8);
    qw1[j * 4 + 0] = v.x; qw1[j * 4 + 1] = v.y;
    qw1[j * 4 + 2] = v.z; qw1[j * 4 + 3] = v.w;
  }
  __syncthreads();

  const size_t tok0 = (size_t)((b * 8 + t) * 1024 + px0);
  u16* mp0 = corr + tok0 * 448 + h * 56;
  u16* mp1 = mp0 + 448;

  for (int du = 0; du < 7; ++du) {
    const int rlb = (yloc + du) * 32;    // staged row 0..13
    float f0[7], f1[7];
#pragma unroll
    for (int ci = 0; ci < 8; ++ci) {
      int col = x0 + ci - 3;                       // absolute col, -3..34
      unsigned inb = ((unsigned)col < 32u);
      int xc = col < 0 ? 0 : (col > 31 ? 31 : col);
      int pl = rlb + xc;
      const char* kr = (const char*)kst + pl * 128;
      const int swz = (pl & 7) << 4;
      uint4 kv[8];
#pragma unroll
      for (int j = 0; j < 8; ++j) kv[j] = *(const uint4*)(kr + ((j * 16) ^ swz));
      if (ci < 7) {                 // px0: dv = ci
        float s = dot64(qw0, kv);
        f0[ci] = inb ? s : 0.f;
      }
      if (ci > 0) {                 // px1: dv = ci-1 (same absolute col)
        float s = dot64(qw1, kv);
        f1[ci - 1] = inb ? s : 0.f;
      }
    }
    uint4 o0, o1;
    o0.x = pkh(f0[0], f0[1]); o0.y = pkh(f0[2], f0[3]);
    o0.z = pkh(f0[4], f0[5]); o0.w = pkh(f0[6], 0.f);
    o1.x = pkh(f1[0], f1[1]); o1.y = pkh(f1[2], f1[3]);
    o1.z = pkh(f1[4], f1[5]); o1.w = pkh(f1[6], 0.f);
    *(uint4*)(mp0 + du * 8) = o0;
    *(uint4*)(mp1 + du * 8) = o1;
  }
}

extern "C" void kernel_launch(void* const* d_in, const int* in_sizes, int n_in,
                              void* d_out, int out_size, void* d_ws, size_t ws_size,
                              hipStream_t stream) {
  const float* x      = (const float*)d_in[0];  // [2,8192,512] f32
  const float* w_qk   = (const float*)d_in[1];  // [1024,512]   f32
  const float* w_corr = (const float*)d_in[2];  // [64,49]      f32
  const float* b_corr = (const float*)d_in[3];  // [64]         f32
  const float* w_proj = (const float*)d_in[4];  // [512,512]    f32
  const float* b_proj = (const float*)d_in[5];  // [512]        f32
  float* out = (float*)d_out;                   // [2,8192,512] f32

  // ws: corr [16384][448] | qf planar [16384][1024]... (f16) | W2 [512][448] | cvec
  u16* corr = (u16*)d_ws;
  u16* qf   = corr + (size_t)16384 * 448;
  u16* W2   = qf + (size_t)16384 * 1024;
  float* cvec = (float*)(W2 + (size_t)512 * 448);

  // qk projection (f32 operands, fused convert, raw-barrier dbuf) + L2 norm
  gemm<0, 1, 8><<<dim3(1024), dim3(256), 0, stream>>>(
      x, w_qk, nullptr, qf, 1024, 512);
  // px-paired cost-volume dots -> corr[16384][448]; W2/cvec prep (merged)
  dots_w2<<<dim3(1024), dim3(128), 0, stream>>>(qf, corr, w_proj, w_corr,
                                                b_corr, b_proj, W2, cvec);
  // out = corr @ W2^T + cvec  (K=448, f16 gld16, BK=64 two-subtile)
  gemm<1, 0, 4><<<dim3(512), dim3(256), 0, stream>>>(
      corr, W2, cvec, out, 512, 448);
}

// Round 15
// 78.164 us; speedup vs baseline: 1.0651x; 1.0651x over previous
//
#include <hip/hip_runtime.h>

typedef unsigned int u32;
typedef unsigned short u16;
typedef __fp16 h2 __attribute__((ext_vector_type(2)));
typedef __fp16 f16x8 __attribute__((ext_vector_type(8)));
typedef float f32x4 __attribute__((ext_vector_type(4)));

#define DEVFN static __device__ __forceinline__

DEVFN u32 pkh(float a, float b) {
  return __builtin_bit_cast(u32, __builtin_amdgcn_cvt_pkrtz(a, b));
}
DEVFN u16 f2h(float f) { __fp16 h = (__fp16)f; return __builtin_bit_cast(u16, h); }

#if __has_builtin(__builtin_amdgcn_fdot2)
DEVFN float dot2u(u32 a, u32 b, float c) {
  return __builtin_amdgcn_fdot2(__builtin_bit_cast(h2, a),
                                __builtin_bit_cast(h2, b), c, false);
}
#else
DEVFN float dot2u(u32 a, u32 b, float c) {
  h2 x = __builtin_bit_cast(h2, a), y = __builtin_bit_cast(h2, b);
  return c + (float)x[0] * (float)y[0] + (float)x[1] * (float)y[1];
}
#endif

DEVFN uint4 pk8(f32x4 lo, f32x4 hi) {
  uint4 o;
  o.x = pkh(lo.x, lo.y); o.y = pkh(lo.z, lo.w);
  o.z = pkh(hi.x, hi.y); o.w = pkh(hi.z, hi.w);
  return o;
}

DEVFN void gld16(const u16* g, u16* l) {
  __builtin_amdgcn_global_load_lds(
      (const __attribute__((address_space(1))) u32*)g,
      (__attribute__((address_space(3))) u32*)l, 16, 0, 0);
}

DEVFN void waitl0() { asm volatile("s_waitcnt lgkmcnt(0)" ::: "memory"); }
DEVFN void rbar() {
  __builtin_amdgcn_sched_barrier(0);
  __builtin_amdgcn_s_barrier();
  __builtin_amdgcn_sched_barrier(0);
}

// GEMM1: C = A @ B^T, A,B f32 reg-staged, dbuf write-late raw-barrier pipeline
// (round-13 verified). Epilogue: L2-normalize each aligned 64-col group, write
// f16 PLANAR qf [sel][b][t][h][1024px][64] (fr = ((sel*2+b)*8+t)*8+h). Nn=1024.
// Tiles: BM=BN=128, BK=32; 4 waves (2x2), 4x4 frags of mfma 16x16x32 f16.
__global__ __launch_bounds__(256) void gemm1(
    const float* __restrict__ Af, const float* __restrict__ Bf,
    u16* __restrict__ Out, int Nn, int K) {
  __shared__ u16 As[2][4096];
  __shared__ u16 Bs[2][4096];
  const int tid = threadIdx.x;
  const int lane = tid & 63;
  const int w = tid >> 6;
  const int wm = w >> 1, wn = w & 1;
  const int nwg = (int)gridDim.x;
  const int wg = ((int)blockIdx.x & 7) * (nwg >> 3) + ((int)blockIdx.x >> 3);
  const int tm = wg >> 3, tn = wg & 7;

  const int rr = tid >> 2;
  const int s8 = (tid & 3) << 3;
  const size_t offA = (size_t)(tm * 128 + rr) * K + s8;
  const size_t offB = (size_t)(tn * 128 + rr) * K + s8;
  const int wofs = rr * 32 + s8;

  const int rofsA = ((wm * 64 + (lane & 15)) << 5) + ((lane >> 4) << 3);
  const int rofsB = ((wn * 64 + (lane & 15)) << 5) + ((lane >> 4) << 3);

  f32x4 acc[4][4] = {};
  f32x4 a0, a1, a2, a3, b0, b1, b2, b3;

#define LOADF(t)                                                          \
  {                                                                       \
    const size_t oa = offA + (size_t)(t) * 32;                            \
    const size_t ob = offB + (size_t)(t) * 32;                            \
    a0 = *(const f32x4*)(Af + oa);                                        \
    a1 = *(const f32x4*)(Af + oa + 4);                                    \
    a2 = *(const f32x4*)(Af + oa + (size_t)64 * K);                       \
    a3 = *(const f32x4*)(Af + oa + (size_t)64 * K + 4);                   \
    b0 = *(const f32x4*)(Bf + ob);                                        \
    b1 = *(const f32x4*)(Bf + ob + 4);                                    \
    b2 = *(const f32x4*)(Bf + ob + (size_t)64 * K);                       \
    b3 = *(const f32x4*)(Bf + ob + (size_t)64 * K + 4);                   \
  }
#define WRITEF(bufi)                                                      \
  {                                                                       \
    u16* da = &As[bufi][wofs];                                            \
    u16* db = &Bs[bufi][wofs];                                            \
    *(uint4*)da = pk8(a0, a1);                                            \
    *(uint4*)(da + 2048) = pk8(a2, a3);                                   \
    *(uint4*)db = pk8(b0, b1);                                            \
    *(uint4*)(db + 2048) = pk8(b2, b3);                                   \
  }

  const int KT = K >> 5;
  LOADF(0)
  WRITEF(0)
  LOADF(1)
  waitl0();
  rbar();
  for (int kt = 0; kt < KT; ++kt) {
    const int cur = kt & 1;
    f16x8 af[4], bf[4];
#pragma unroll
    for (int i = 0; i < 4; ++i) af[i] = *(const f16x8*)(&As[cur][rofsA + i * 512]);
#pragma unroll
    for (int i = 0; i < 4; ++i) bf[i] = *(const f16x8*)(&Bs[cur][rofsB + i * 512]);
    if (kt + 1 < KT) {
      WRITEF(cur ^ 1)
      if (kt + 2 < KT) LOADF(kt + 2)
    }
    __builtin_amdgcn_s_setprio(1);
#pragma unroll
    for (int mi = 0; mi < 4; ++mi)
#pragma unroll
      for (int ni = 0; ni < 4; ++ni)
        acc[mi][ni] = __builtin_amdgcn_mfma_f32_16x16x32_f16(af[mi], bf[ni],
                                                             acc[mi][ni], 0, 0, 0);
    __builtin_amdgcn_s_setprio(0);
    waitl0();
    rbar();
  }
#undef LOADF
#undef WRITEF

  // C/D layout: col = lane&15, row = (lane>>4)*4 + r
  const int rowBase = tm * 128 + wm * 64 + ((lane >> 4) << 2);
  const int colBase = tn * 128 + wn * 64 + (lane & 15);
  const int sel = colBase >> 9;
  const int hh = (colBase >> 6) & 7;
  const int ddb = lane & 15;
#pragma unroll
  for (int mi = 0; mi < 4; ++mi)
#pragma unroll
    for (int r = 0; r < 4; ++r) {
      float s = acc[mi][0][r] * acc[mi][0][r] + acc[mi][1][r] * acc[mi][1][r] +
                acc[mi][2][r] * acc[mi][2][r] + acc[mi][3][r] * acc[mi][3][r];
      s += __shfl_xor(s, 1);
      s += __shfl_xor(s, 2);
      s += __shfl_xor(s, 4);
      s += __shfl_xor(s, 8);
      float inv = 1.0f / fmaxf(sqrtf(s), 1e-12f);
      const int m = rowBase + mi * 16 + r;
      const int bb = m >> 13, tt = (m >> 10) & 7, pix = m & 1023;
      const int fr = ((sel * 2 + bb) * 8 + tt) * 8 + hh;
      size_t base = (((size_t)fr) << 16) + (size_t)pix * 64 + ddb;
#pragma unroll
      for (int ni = 0; ni < 4; ++ni)
        Out[base + ni * 16] = f2h(acc[mi][ni][r] * inv);
    }
}

// GEMM2b: out = A @ B^T + bias.  A [M][448] f16 (corr), B [512][448] f16 (W2).
// BM=64 x BN=128 -> 1024 blocks (4/CU), BK=64 as two [.][32] subtiles/round.
// 4 waves: wave w owns rows 0..63 x cols w*32..w*32+31 (acc[4][2]).
__global__ __launch_bounds__(256) void gemm2b(
    const u16* __restrict__ A, const u16* __restrict__ B,
    const float* __restrict__ bias, float* __restrict__ Out,
    int Nn, int K) {
  __shared__ u16 As[2][2048];   // [64][32] per subtile
  __shared__ u16 Bs[2][4096];   // [128][32]
  const int tid = threadIdx.x;
  const int lane = tid & 63;
  const int w = tid >> 6;
  const int nwg = (int)gridDim.x;
  const int wg = ((int)blockIdx.x & 7) * (nwg >> 3) + ((int)blockIdx.x >> 3);
  const int tm = wg >> 2, tn = wg & 3;

  // gld16: wave w stages A rows w*16..+15 (1 call) and B rows w*32..+31 (2)
  const u16* gA = A + (size_t)(tm * 64 + w * 16 + (lane >> 2)) * K +
                  ((lane & 3) << 3);
  const u16* gB = B + (size_t)(tn * 128 + w * 32 + (lane >> 2)) * K +
                  ((lane & 3) << 3);

  // fragment read bases
  const int rofsA = ((lane & 15) << 5) + ((lane >> 4) << 3);          // + mi*512
  const int rofsB = w * 1024 + ((lane & 15) << 5) + ((lane >> 4) << 3);  // + ni*512

  f32x4 acc[4][2] = {};

#define STG(bufi, t)                                                      \
  {                                                                       \
    gld16(gA + (size_t)(t) * 32, &As[bufi][w * 512]);                     \
    gld16(gB + (size_t)(t) * 32, &Bs[bufi][w * 1024]);                    \
    gld16(gB + (size_t)(t) * 32 + (size_t)16 * K, &Bs[bufi][w * 1024 + 512]); \
  }

  const int KT = K >> 6;   // 448/64 = 7
  for (int kt = 0; kt < KT; ++kt) {
    __syncthreads();
    STG(0, 2 * kt)
    STG(1, 2 * kt + 1)
    __syncthreads();
#pragma unroll
    for (int sub = 0; sub < 2; ++sub) {
      f16x8 af[4], bf[2];
#pragma unroll
      for (int i = 0; i < 4; ++i)
        af[i] = *(const f16x8*)(&As[sub][rofsA + i * 512]);
#pragma unroll
      for (int i = 0; i < 2; ++i)
        bf[i] = *(const f16x8*)(&Bs[sub][rofsB + i * 512]);
#pragma unroll
      for (int mi = 0; mi < 4; ++mi)
#pragma unroll
        for (int ni = 0; ni < 2; ++ni)
          acc[mi][ni] = __builtin_amdgcn_mfma_f32_16x16x32_f16(
              af[mi], bf[ni], acc[mi][ni], 0, 0, 0);
    }
  }
#undef STG

  const int rowBase = tm * 64 + ((lane >> 4) << 2);
  const int colBase = tn * 128 + w * 32 + (lane & 15);
  float bv[2];
#pragma unroll
  for (int ni = 0; ni < 2; ++ni) bv[ni] = bias[colBase + ni * 16];
#pragma unroll
  for (int mi = 0; mi < 4; ++mi)
#pragma unroll
    for (int r = 0; r < 4; ++r) {
      size_t ro = (size_t)(rowBase + mi * 16 + r) * Nn;
#pragma unroll
      for (int ni = 0; ni < 2; ++ni)
        Out[ro + colBase + ni * 16] = acc[mi][ni][r] + bv[ni];
    }
}

// Merged, 256 threads: blocks 0..511 = dots (round-13 structure, corr[448]);
// blocks 512..1023 = W2[512][448] + cvec prep.
__global__ __launch_bounds__(256) void dots_w2(
    const u16* __restrict__ qf, u16* __restrict__ corr,
    const float* __restrict__ wp, const float* __restrict__ wc,
    const float* __restrict__ bc, const float* __restrict__ bp,
    u16* __restrict__ W2, float* __restrict__ cvec) {
  __shared__ __align__(16) u16 smem[448 * 64];  // 56KB
  const int tid = threadIdx.x;

  if ((int)blockIdx.x >= 512) {
    const int o = (int)blockIdx.x - 512;
    float* wcl = (float*)smem;        // [64*49]
    float* wpl = wcl + 3136;          // [512]
    for (int i = tid; i < 3136; i += 256) wcl[i] = wc[i];
    wpl[tid] = wp[o * 512 + tid];
    wpl[tid + 256] = wp[o * 512 + tid + 256];
    __syncthreads();
#pragma unroll
    for (int pass = 0; pass < 2; ++pass) {
      const int idx = pass * 256 + tid;      // 0..511
      if (idx < 448) {
        const int hh = idx / 56, r = idx % 56, du = r >> 3, dv = r & 7;
        float sv = 0.f;
        if (dv < 7) {
#pragma unroll
          for (int c = 0; c < 64; ++c)
            sv += wpl[hh * 64 + c] * wcl[c * 49 + du * 7 + dv];
        }
        W2[o * 448 + idx] = f2h(sv);
      }
    }
    if (tid < 64) {
      float p = 0.f;
#pragma unroll
      for (int g = 0; g < 8; ++g) p += wpl[g * 64 + tid];
      p *= bc[tid];
      p += __shfl_xor(p, 1); p += __shfl_xor(p, 2); p += __shfl_xor(p, 4);
      p += __shfl_xor(p, 8); p += __shfl_xor(p, 16); p += __shfl_xor(p, 32);
      if (tid == 0) cvec[o] = p + bp[o];
    }
    return;
  }

  // ---- dots (round-13 structure) ----
  u16* kst = smem;
  const int bid = ((int)blockIdx.x & 7) * 64 + ((int)blockIdx.x >> 3);  // XCD
  const int fr = bid >> 2, grp = bid & 3;
  const int h = fr & 7, t = (fr >> 3) & 7, b = fr >> 6;
  const int t1 = (t < 7) ? t + 1 : 7;
  const int y0 = grp * 8;

  const u16* kbase = qf + (((size_t)(((2 + b) * 8 + t1) * 8 + h)) << 16);
  {
    const int ppx = tid >> 3;
    const int slot = tid & 7;
#pragma unroll
    for (int pass = 0; pass < 14; ++pass) {
      int gy = y0 - 3 + pass;
      uint4 v = make_uint4(0, 0, 0, 0);
      if ((unsigned)gy < 32u)
        v = *(const uint4*)(kbase + (size_t)(gy * 32 + ppx) * 64 + slot * 8);
      int pl = pass * 32 + ppx;
      *(uint4*)((char*)kst + pl * 128 + ((slot * 16) ^ ((pl & 7) << 4))) = v;
    }
  }

  const int px = grp * 256 + tid;
  const int x = tid & 31, yloc = tid >> 5;
  const u16* qp = qf + (((size_t)fr) << 16) + (size_t)px * 64;
  u32 qw[32];
#pragma unroll
  for (int j = 0; j < 8; ++j) {
    uint4 v = *(const uint4*)(qp + j * 8);
    qw[j * 4 + 0] = v.x; qw[j * 4 + 1] = v.y;
    qw[j * 4 + 2] = v.z; qw[j * 4 + 3] = v.w;
  }
  __syncthreads();

  u16* mp = corr + (size_t)((b * 8 + t) * 1024 + px) * 448 + h * 56;
  for (int du = 0; du < 7; ++du) {
    const int rlbase = (yloc + du) * 32;
    float f[7];
#pragma unroll
    for (int dv = 0; dv < 7; ++dv) {
      int xx = x + dv - 3;
      int xc = xx < 0 ? 0 : (xx > 31 ? 31 : xx);
      int pl = rlbase + xc;
      const char* kr = (const char*)kst + pl * 128;
      const int swz = (pl & 7) << 4;
      float s0 = 0.f, s1 = 0.f, s2 = 0.f, s3 = 0.f;
#pragma unroll
      for (int j = 0; j < 8; ++j) {
        uint4 v = *(const uint4*)(kr + ((j * 16) ^ swz));
        s0 = dot2u(qw[j * 4 + 0], v.x, s0);
        s1 = dot2u(qw[j * 4 + 1], v.y, s1);
        s2 = dot2u(qw[j * 4 + 2], v.z, s2);
        s3 = dot2u(qw[j * 4 + 3], v.w, s3);
      }
      float s = (s0 + s1) + (s2 + s3);
      f[dv] = ((unsigned)xx < 32u) ? s : 0.f;
    }
    uint4 o;
    o.x = pkh(f[0], f[1]); o.y = pkh(f[2], f[3]);
    o.z = pkh(f[4], f[5]); o.w = pkh(f[6], 0.f);
    *(uint4*)(mp + du * 8) = o;   // 7 stores cover exactly 56 cols
  }
}

extern "C" void kernel_launch(void* const* d_in, const int* in_sizes, int n_in,
                              void* d_out, int out_size, void* d_ws, size_t ws_size,
                              hipStream_t stream) {
  const float* x      = (const float*)d_in[0];  // [2,8192,512] f32
  const float* w_qk   = (const float*)d_in[1];  // [1024,512]   f32
  const float* w_corr = (const float*)d_in[2];  // [64,49]      f32
  const float* b_corr = (const float*)d_in[3];  // [64]         f32
  const float* w_proj = (const float*)d_in[4];  // [512,512]    f32
  const float* b_proj = (const float*)d_in[5];  // [512]        f32
  float* out = (float*)d_out;                   // [2,8192,512] f32

  // ws: corr [16384][448] | qf planar (32MB) | W2 [512][448] | cvec
  u16* corr = (u16*)d_ws;
  u16* qf   = corr + (size_t)16384 * 448;
  u16* W2   = qf + (size_t)16384 * 1024;
  float* cvec = (float*)(W2 + (size_t)512 * 448);

  // qk projection (f32 operands, fused convert, raw-barrier dbuf) + L2 norm
  gemm1<<<dim3(1024), dim3(256), 0, stream>>>(x, w_qk, qf, 1024, 512);
  // cost-volume dots -> corr[16384][448]; W2/cvec prep (merged)
  dots_w2<<<dim3(1024), dim3(256), 0, stream>>>(qf, corr, w_proj, w_corr,
                                                b_corr, b_proj, W2, cvec);
  // out = corr @ W2^T + cvec  (K=448, BM=64 high-occupancy gld16)
  gemm2b<<<dim3(1024), dim3(256), 0, stream>>>(corr, W2, b_proj ? cvec : cvec,
                                               out, 512, 448);
}